// Round 2
// baseline (742.794 us; speedup 1.0000x reference)
//
#include <hip/hip_runtime.h>

// Block-diagonal transform (x-row chunks @ h) + per-row dynamic int8 quant.
// m=n=8192, k=64. One block per row; 4 waves x 32 chunks per wave.
// Lane j keeps h-column j resident in 64 VGPRs; x chunk is wave-uniform.
// Output: int8 values materialized as int32 in d_out (harness decodes np.int32).

constexpr int Ncols = 8192;
constexpr int Kdim  = 64;
constexpr int NWAVES = 4;
constexpr int CPW = (Ncols / Kdim) / NWAVES;  // 32 chunks per wave

__global__ __launch_bounds__(256, 4)
void bdq_kernel(const float* __restrict__ x,
                const float* __restrict__ h,
                int* __restrict__ out)
{
    __shared__ float sres[Ncols];      // 32 KB: this block's transformed row
    __shared__ float swmax[NWAVES];

    const int tid  = threadIdx.x;
    const int lane = tid & 63;
    const int wave = __builtin_amdgcn_readfirstlane(tid >> 6);
    const int row  = blockIdx.x;

    // h column `lane` -> 64 registers (coalesced 256B loads, L1/L2-hot)
    float hc[Kdim];
#pragma unroll
    for (int k = 0; k < Kdim; ++k) hc[k] = h[k * Kdim + lane];

    const float* xw = x + (size_t)row * Ncols + (size_t)wave * (CPW * Kdim);
    float* sw = sres + wave * (CPW * Kdim);

    float lmax = 0.0f;
    for (int c = 0; c < CPW; ++c) {
        // wave-uniform chunk pointer: uniform loads (scalarizable)
        const float4* xc = (const float4*)(xw + c * Kdim);
        float a0 = 0.f, a1 = 0.f, a2 = 0.f, a3 = 0.f;
#pragma unroll
        for (int i = 0; i < 16; ++i) {
            float4 v = xc[i];
            a0 = fmaf(v.x, hc[4 * i + 0], a0);
            a1 = fmaf(v.y, hc[4 * i + 1], a1);
            a2 = fmaf(v.z, hc[4 * i + 2], a2);
            a3 = fmaf(v.w, hc[4 * i + 3], a3);
        }
        float r = (a0 + a1) + (a2 + a3);
        sw[c * Kdim + lane] = r;            // conflict-free (lane-consecutive)
        lmax = fmaxf(lmax, fabsf(r));
    }

    // wave-level max reduce over 64 lanes
#pragma unroll
    for (int off = 32; off > 0; off >>= 1)
        lmax = fmaxf(lmax, __shfl_xor(lmax, off, 64));
    if (lane == 0) swmax[wave] = lmax;
    __syncthreads();

    float rmax = fmaxf(fmaxf(swmax[0], swmax[1]), fmaxf(swmax[2], swmax[3]));
    // scale = rmax/127; y = round(r/scale). Guard all-zero row (r==0 -> y=0).
    float inv = (rmax > 0.f) ? (127.0f / rmax) : 0.0f;

    int* ow = out + (size_t)row * Ncols + (size_t)wave * (CPW * Kdim);
#pragma unroll 4
    for (int c = 0; c < CPW; ++c) {
        float r = sw[c * Kdim + lane];
        float q = rintf(r * inv);           // rintf = round-half-even, matches np
        q = fminf(fmaxf(q, -128.f), 127.f);
        ow[c * Kdim + lane] = (int)q;       // int32 out, coalesced 256B/wave-instr
    }
}

extern "C" void kernel_launch(void* const* d_in, const int* in_sizes, int n_in,
                              void* d_out, int out_size, void* d_ws, size_t ws_size,
                              hipStream_t stream) {
    const float* x = (const float*)d_in[0];   // [8192, 8192]
    const float* h = (const float*)d_in[1];   // [64, 64]
    int* out = (int*)d_out;                   // [8192, 8192] int8 values as int32
    dim3 grid(8192), block(256);
    hipLaunchKernelGGL(bdq_kernel, grid, block, 0, stream, x, h, out);
}

// Round 3
// 491.104 us; speedup vs baseline: 1.5125x; 1.5125x over previous
//
#include <hip/hip_runtime.h>

// Block-diagonal transform (x-row chunks @ h) + per-row dynamic int8 quant.
// One block per row, 4 waves x 32 chunks. Lane j holds h column j in 64 VGPRs.
// x is staged per-wave into LDS with coalesced per-lane loads (1 KiB/instr),
// then broadcast-read via uniform ds_read_b128 (conflict-free). Results stay
// in registers (32/lane). Output int8 values as int32 (harness decodes int32).

constexpr int Ncols  = 8192;
constexpr int Kdim   = 64;
constexpr int NWAVES = 4;
constexpr int CPW    = (Ncols / Kdim) / NWAVES;  // 32 chunks per wave
constexpr int SEG    = CPW * Kdim;               // 2048 floats per wave segment

__global__ __launch_bounds__(256, 4)
void bdq_kernel(const float* __restrict__ x,
                const float* __restrict__ h,
                int* __restrict__ out)
{
    __shared__ float sx[NWAVES * SEG];   // 32 KB x staging
    __shared__ float swmax[NWAVES];

    const int tid  = threadIdx.x;
    const int lane = tid & 63;
    const int wave = tid >> 6;
    const int row  = blockIdx.x;

    // h column `lane` -> 64 registers (L2-hot, coalesced)
    float hc[Kdim];
#pragma unroll
    for (int k = 0; k < Kdim; ++k) hc[k] = h[k * Kdim + lane];

    // Stage this wave's 8 KB segment: 8 coalesced float4 loads (1 KiB unique/instr)
    const float4* xg = (const float4*)(x + (size_t)row * Ncols + (size_t)wave * SEG);
    float4* sg = (float4*)(sx + wave * SEG);
#pragma unroll
    for (int i = 0; i < 8; ++i)
        sg[i * 64 + lane] = xg[i * 64 + lane];
    // Only this wave reads its own segment -> no __syncthreads needed here;
    // compiler inserts vmcnt/lgkmcnt waits for the RAW hazard.

    const float* sw = sx + wave * SEG;
    float r[CPW];
    float lmax = 0.0f;
    for (int c = 0; c < CPW; ++c) {
        const float4* xc = (const float4*)(sw + c * Kdim);  // uniform -> broadcast
        float a0 = 0.f, a1 = 0.f, a2 = 0.f, a3 = 0.f;
#pragma unroll
        for (int i = 0; i < 16; ++i) {
            float4 v = xc[i];                // ds_read_b128, all lanes same addr
            a0 = fmaf(v.x, hc[4 * i + 0], a0);
            a1 = fmaf(v.y, hc[4 * i + 1], a1);
            a2 = fmaf(v.z, hc[4 * i + 2], a2);
            a3 = fmaf(v.w, hc[4 * i + 3], a3);
        }
        float rr = (a0 + a1) + (a2 + a3);
        r[c] = rr;
        lmax = fmaxf(lmax, fabsf(rr));
    }

    // wave max over 64 lanes
#pragma unroll
    for (int off = 32; off > 0; off >>= 1)
        lmax = fmaxf(lmax, __shfl_xor(lmax, off, 64));
    if (lane == 0) swmax[wave] = lmax;
    __syncthreads();

    float rmax = fmaxf(fmaxf(swmax[0], swmax[1]), fmaxf(swmax[2], swmax[3]));
    float inv = (rmax > 0.f) ? (127.0f / rmax) : 0.0f;   // all-zero row -> 0

    int* ow = out + (size_t)row * Ncols + (size_t)wave * SEG;
#pragma unroll 4
    for (int c = 0; c < CPW; ++c) {
        float q = rintf(r[c] * inv);         // half-to-even, matches np.round
        q = fminf(fmaxf(q, -128.f), 127.f);
        ow[c * Kdim + lane] = (int)q;        // coalesced 256 B per wave-instr
    }
}

extern "C" void kernel_launch(void* const* d_in, const int* in_sizes, int n_in,
                              void* d_out, int out_size, void* d_ws, size_t ws_size,
                              hipStream_t stream) {
    const float* x = (const float*)d_in[0];   // [8192, 8192]
    const float* h = (const float*)d_in[1];   // [64, 64]
    int* out = (int*)d_out;                   // [8192, 8192] int8 values as int32
    dim3 grid(8192), block(256);
    hipLaunchKernelGGL(bdq_kernel, grid, block, 0, stream, x, h, out);
}

// Round 4
// 437.703 us; speedup vs baseline: 1.6970x; 1.1220x over previous
//
#include <hip/hip_runtime.h>

// Block-diagonal transform via MFMA f16 + per-row dynamic int8 quant.
// R[1M x 64] = X[1M x 64] @ H[64 x 64]; original row = 128 X-rows (chunks).
// Block = 256 thr (4 waves) = 1 original row. Wave = 32 chunks:
//   2 row-tiles x 4 col-tiles x 2 K-steps of mfma_f32_16x16x32_f16.
// Accumulators keep the whole wave output (32 f32/lane); h frags resident
// (32 VGPR, loaded once). Output: int8 values as int32 (harness decodes i32).

typedef _Float16 half8_t __attribute__((ext_vector_type(8)));
typedef float float4_t __attribute__((ext_vector_type(4)));

constexpr int Ncols  = 8192;
constexpr int Kdim   = 64;
constexpr int NWAVES = 4;

__global__ __launch_bounds__(256, 4)
void bdq_mfma(const float* __restrict__ x,
              const float* __restrict__ h,
              int* __restrict__ out)
{
    __shared__ float swmax[NWAVES];

    const int tid  = threadIdx.x;
    const int lane = tid & 63;
    const int wave = tid >> 6;
    const int quad = lane >> 4;   // 0..3
    const int l16  = lane & 15;
    const int row  = blockIdx.x;

    // B frags: lane holds col = ct*16+l16, k = ks*32 + quad*8 + j (j=0..7).
    // h is [k][col] row-major; loads are 64B-contiguous per 16-lane quad, L2-hot.
    half8_t bfrag[2][4];
#pragma unroll
    for (int ks = 0; ks < 2; ++ks)
#pragma unroll
        for (int ct = 0; ct < 4; ++ct) {
            const int k0  = ks * 32 + quad * 8;
            const int col = ct * 16 + l16;
            half8_t b;
#pragma unroll
            for (int j = 0; j < 8; ++j)
                b[j] = (_Float16)h[(k0 + j) * Kdim + col];
            bfrag[ks][ct] = b;
        }

    const float* xrow = x + (size_t)row * Ncols;

    float4_t acc[2][4];
#pragma unroll
    for (int rt = 0; rt < 2; ++rt)
#pragma unroll
        for (int ct = 0; ct < 4; ++ct)
            acc[rt][ct] = (float4_t){0.f, 0.f, 0.f, 0.f};

    // A frags: lane holds X-row (chunk) = wave*32 + rt*16 + l16,
    // k = ks*32 + quad*8 + j -> 8 consecutive f32 -> 2 x float4 loads.
#pragma unroll
    for (int rt = 0; rt < 2; ++rt) {
#pragma unroll
        for (int ks = 0; ks < 2; ++ks) {
            const int chunk = wave * 32 + rt * 16 + l16;
            const int k0    = ks * 32 + quad * 8;
            const float4* p = (const float4*)(xrow + chunk * Kdim + k0);
            float4 v0 = p[0], v1 = p[1];
            half8_t a;
            a[0] = (_Float16)v0.x; a[1] = (_Float16)v0.y;
            a[2] = (_Float16)v0.z; a[3] = (_Float16)v0.w;
            a[4] = (_Float16)v1.x; a[5] = (_Float16)v1.y;
            a[6] = (_Float16)v1.z; a[7] = (_Float16)v1.w;
#pragma unroll
            for (int ct = 0; ct < 4; ++ct)
                acc[rt][ct] = __builtin_amdgcn_mfma_f32_16x16x32_f16(
                    a, bfrag[ks][ct], acc[rt][ct], 0, 0, 0);
        }
    }

    // Row absmax: per-lane over 32 acc values -> wave shfl-reduce -> LDS.
    float lmax = 0.0f;
#pragma unroll
    for (int rt = 0; rt < 2; ++rt)
#pragma unroll
        for (int ct = 0; ct < 4; ++ct)
#pragma unroll
            for (int i = 0; i < 4; ++i)
                lmax = fmaxf(lmax, fabsf(acc[rt][ct][i]));
#pragma unroll
    for (int off = 32; off > 0; off >>= 1)
        lmax = fmaxf(lmax, __shfl_xor(lmax, off, 64));
    if (lane == 0) swmax[wave] = lmax;
    __syncthreads();

    const float rmax = fmaxf(fmaxf(swmax[0], swmax[1]),
                             fmaxf(swmax[2], swmax[3]));
    const float inv = (rmax > 0.f) ? (127.0f / rmax) : 0.0f;  // zero row -> 0

    // C/D: col = ct*16 + l16, X-row = wave*32 + rt*16 + quad*4 + i.
    int* orow = out + (size_t)row * Ncols;
#pragma unroll
    for (int rt = 0; rt < 2; ++rt)
#pragma unroll
        for (int ct = 0; ct < 4; ++ct)
#pragma unroll
            for (int i = 0; i < 4; ++i) {
                const int chunk = wave * 32 + rt * 16 + quad * 4 + i;
                const int col   = ct * 16 + l16;
                float q = rintf(acc[rt][ct][i] * inv);  // half-even = np.round
                q = fminf(fmaxf(q, -128.f), 127.f);
                orow[chunk * Kdim + col] = (int)q;
            }
}

extern "C" void kernel_launch(void* const* d_in, const int* in_sizes, int n_in,
                              void* d_out, int out_size, void* d_ws, size_t ws_size,
                              hipStream_t stream) {
    const float* x = (const float*)d_in[0];   // [8192, 8192]
    const float* h = (const float*)d_in[1];   // [64, 64]
    int* out = (int*)d_out;                   // [8192, 8192] int8 values as int32
    dim3 grid(8192), block(256);
    hipLaunchKernelGGL(bdq_mfma, grid, block, 0, stream, x, h, out);
}